// Round 1
// baseline (585.747 us; speedup 1.0000x reference)
//
#include <hip/hip_runtime.h>
#include <hip/hip_bf16.h>
#include <math.h>

#define M_TOT 4096
#define K_TOT 1024
#define V_TOT 32000
#define BM 128
#define BN 128
#define BK 32
#define NT (K_TOT / BK)

typedef short short8 __attribute__((ext_vector_type(8)));
typedef float f32x4 __attribute__((ext_vector_type(4)));

__device__ __forceinline__ void gload_lds16(const void* g, void* l) {
  __builtin_amdgcn_global_load_lds(
      (const __attribute__((address_space(1))) void*)g,
      (__attribute__((address_space(3))) void*)l, 16, 0, 0);
}

__device__ __forceinline__ unsigned short f2bf(float f) {
  // round-to-nearest-even fp32 -> bf16 (inputs are sanitized/finite)
  unsigned int u = __builtin_bit_cast(unsigned int, f);
  unsigned int lsb = (u >> 16) & 1u;
  u += 0x7fffu + lsb;
  return (unsigned short)(u >> 16);
}

__device__ __forceinline__ float sani(float v) {
  return (v != v) ? 0.0f : fminf(fmaxf(v, -1e4f), 1e4f);
}

// hidden_states [4096][1025] fp32 -> h0 fp32 [4096], hbf bf16 [4096][1024]
__global__ void prep_h(const float* __restrict__ h, unsigned short* __restrict__ hbf,
                       float* __restrict__ h0) {
  int m = blockIdx.x;
  int t = threadIdx.x;
  const float* row = h + (long)m * (K_TOT + 1);
  if (t == 0) h0[m] = sani(row[0]);
  unsigned short* dst = hbf + (long)m * K_TOT;
#pragma unroll
  for (int j = 0; j < 4; ++j) {
    int idx = t * 4 + j;
    dst[idx] = f2bf(sani(row[1 + idx]));
  }
}

// weight [32000][1024] fp32 -> wtime fp32 [V], wbf = bf16(r * w) [V][1024]
__global__ void prep_w(const float* __restrict__ w, unsigned short* __restrict__ wbf,
                       float* __restrict__ wtime) {
  __shared__ float red[4];
  __shared__ float r_sh;
  int v = blockIdx.x;
  int t = threadIdx.x;
  const float* row = w + (long)v * K_TOT;
  float4 x = *(const float4*)(row + t * 4);
  float s = x.x * x.x + x.y * x.y + x.z * x.z + x.w * x.w;
#pragma unroll
  for (int off = 32; off > 0; off >>= 1) s += __shfl_down(s, off);
  int lane = t & 63, wv = t >> 6;
  if (lane == 0) red[wv] = s;
  __syncthreads();
  if (t == 0) {
    float tot = red[0] + red[1] + red[2] + red[3];
    float norm = sqrtf(tot);
    float r = (norm > 1e-7f) ? (sinhf(norm) / fmaxf(norm, 1e-7f)) : 1.0f;
    r_sh = r;
    wtime[v] = coshf(norm);
  }
  __syncthreads();
  float r = r_sh;
  ushort4 pack;
  pack.x = f2bf(r * x.x);
  pack.y = f2bf(r * x.y);
  pack.z = f2bf(r * x.z);
  pack.w = f2bf(r * x.w);
  *(ushort4*)(wbf + (long)v * K_TOT + t * 4) = pack;
}

__global__ __launch_bounds__(256) void gemm_geo(
    const unsigned short* __restrict__ hbf, const unsigned short* __restrict__ wbf,
    const float* __restrict__ h0, const float* __restrict__ wtime,
    const float* __restrict__ ls, float* __restrict__ out) {
  __shared__ __align__(16) short lds[2][2][BM * BK];  // [buf][A=0,B=1][row*32+k]

  int bid = blockIdx.x;
  // XCD swizzle (8000 blocks % 8 == 0): contiguous 1000-block chunk per XCD;
  // within a chunk, 32 consecutive blocks share one B-panel (v-tile) -> L2 reuse.
  int s = (bid & 7) * 1000 + (bid >> 3);
  int tile_v = s / 32;  // [0,250)
  int tile_m = s % 32;  // [0,32)
  int row0 = tile_m * BM;
  int col0 = tile_v * BN;

  int t = threadIdx.x;
  int wave = t >> 6, lane = t & 63;

  auto stage = [&](int buf, int kt) {
#pragma unroll
    for (int i = 0; i < 2; ++i) {
      int tt = i * 256 + t;
      int r = tt >> 2, c = (tt & 3) * 8;
      const unsigned short* gA = hbf + (long)(row0 + r) * K_TOT + kt * BK + c;
      const unsigned short* gB = wbf + (long)(col0 + r) * K_TOT + kt * BK + c;
      int ldsoff = (i * 256 + wave * 64) * 8;  // shorts; HW adds lane*16B
      gload_lds16(gA, (void*)&lds[buf][0][ldsoff]);
      gload_lds16(gB, (void*)&lds[buf][1][ldsoff]);
    }
  };

  f32x4 acc[4][4];
#pragma unroll
  for (int i = 0; i < 4; ++i)
#pragma unroll
    for (int j = 0; j < 4; ++j) acc[i][j] = (f32x4)(0.0f);

  int wm = wave >> 1, wn = wave & 1;  // 2x2 wave grid, 64x64 per wave
  int fr = lane & 15, fq = lane >> 4;

  stage(0, 0);
  int cur = 0;
  for (int kt = 0; kt < NT; ++kt) {
    __syncthreads();  // staging of buf[cur] complete (compiler drains vmcnt)
    if (kt + 1 < NT) stage(cur ^ 1, kt + 1);
    short8 a[4], b[4];
#pragma unroll
    for (int mi = 0; mi < 4; ++mi) {
      int row = wm * 64 + mi * 16 + fr;
      a[mi] = *(const short8*)&lds[cur][0][row * BK + fq * 8];
    }
#pragma unroll
    for (int ni = 0; ni < 4; ++ni) {
      int row = wn * 64 + ni * 16 + fr;
      b[ni] = *(const short8*)&lds[cur][1][row * BK + fq * 8];
    }
#pragma unroll
    for (int mi = 0; mi < 4; ++mi)
#pragma unroll
      for (int ni = 0; ni < 4; ++ni)
        acc[mi][ni] = __builtin_amdgcn_mfma_f32_16x16x32_bf16(a[mi], b[ni], acc[mi][ni], 0, 0, 0);
    cur ^= 1;
  }

  // fused epilogue: x = h0*w_time - dot ; d = safe_acosh(x) ; out = -tau*d^2
  float tau = fminf(fmaxf(ls[0], 0.01f), 2.5f);
  float wt[4];
#pragma unroll
  for (int ni = 0; ni < 4; ++ni) wt[ni] = wtime[col0 + wn * 64 + ni * 16 + fr];
#pragma unroll
  for (int mi = 0; mi < 4; ++mi) {
#pragma unroll
    for (int j = 0; j < 4; ++j) {
      int m = row0 + wm * 64 + mi * 16 + fq * 4 + j;
      float h0v = h0[m];
#pragma unroll
      for (int ni = 0; ni < 4; ++ni) {
        int v = col0 + wn * 64 + ni * 16 + fr;
        float dot = acc[mi][ni][j];
        float x = h0v * wt[ni] - dot;
        float xm1 = fmaxf(x - 1.0f, 0.0f);
        float d;
        if (xm1 < 1e-3f)
          d = sqrtf(2.0f * fmaxf(xm1, 1e-12f)) * (1.0f - xm1 * (1.0f / 12.0f));
        else
          d = logf(x + sqrtf(x * x - 1.0f));
        float lg = -tau * d * d;
        lg = (lg != lg) ? 0.0f : fminf(fmaxf(lg, -1e4f), 1e4f);
        out[(long)m * V_TOT + v] = lg;
      }
    }
  }
}

extern "C" void kernel_launch(void* const* d_in, const int* in_sizes, int n_in,
                              void* d_out, int out_size, void* d_ws, size_t ws_size,
                              hipStream_t stream) {
  const float* h = (const float*)d_in[0];   // [2,2048,1025]
  const float* w = (const float*)d_in[1];   // [32000,1024]
  const float* ls = (const float*)d_in[2];  // scalar
  float* out = (float*)d_out;               // [2,2048,32000] fp32

  char* ws = (char*)d_ws;
  unsigned short* wbf = (unsigned short*)ws;                              // 65,536,000 B
  unsigned short* hbf = (unsigned short*)(ws + 65536000);                 // 8,388,608 B
  float* wtime = (float*)(ws + 65536000 + 8388608);                       // 128,000 B
  float* h0 = (float*)(ws + 65536000 + 8388608 + 128000);                 // 16,384 B

  prep_h<<<M_TOT, 256, 0, stream>>>(h, hbf, h0);
  prep_w<<<V_TOT, 256, 0, stream>>>(w, wbf, wtime);
  gemm_geo<<<8000, 256, 0, stream>>>(hbf, wbf, h0, wtime, ls, out);
}

// Round 2
// 502.466 us; speedup vs baseline: 1.1657x; 1.1657x over previous
//
#include <hip/hip_runtime.h>
#include <hip/hip_bf16.h>
#include <math.h>

#define M_TOT 4096
#define K_TOT 1024
#define V_TOT 32000
#define BM 128
#define BN 128
#define BK 32
#define NT (K_TOT / BK)

typedef short short8 __attribute__((ext_vector_type(8)));
typedef float f32x4 __attribute__((ext_vector_type(4)));

__device__ __forceinline__ void gload_lds16(const void* g, void* l) {
  __builtin_amdgcn_global_load_lds(
      (const __attribute__((address_space(1))) void*)g,
      (__attribute__((address_space(3))) void*)l, 16, 0, 0);
}

__device__ __forceinline__ unsigned short f2bf(float f) {
  // round-to-nearest-even fp32 -> bf16 (inputs are sanitized/finite)
  unsigned int u = __builtin_bit_cast(unsigned int, f);
  unsigned int lsb = (u >> 16) & 1u;
  u += 0x7fffu + lsb;
  return (unsigned short)(u >> 16);
}

__device__ __forceinline__ float sani(float v) {
  return (v != v) ? 0.0f : fminf(fmaxf(v, -1e4f), 1e4f);
}

// hidden_states [4096][1025] fp32 -> h0 fp32 [4096], hbf bf16 [4096][1024]
__global__ void prep_h(const float* __restrict__ h, unsigned short* __restrict__ hbf,
                       float* __restrict__ h0) {
  int m = blockIdx.x;
  int t = threadIdx.x;
  const float* row = h + (long)m * (K_TOT + 1);
  if (t == 0) h0[m] = sani(row[0]);
  unsigned short* dst = hbf + (long)m * K_TOT;
#pragma unroll
  for (int j = 0; j < 4; ++j) {
    int idx = t * 4 + j;
    dst[idx] = f2bf(sani(row[1 + idx]));
  }
}

// weight [32000][1024] fp32 -> wtime fp32 [V], wbf = bf16(r * w) [V][1024]
__global__ void prep_w(const float* __restrict__ w, unsigned short* __restrict__ wbf,
                       float* __restrict__ wtime) {
  __shared__ float red[4];
  __shared__ float r_sh;
  int v = blockIdx.x;
  int t = threadIdx.x;
  const float* row = w + (long)v * K_TOT;
  float4 x = *(const float4*)(row + t * 4);
  float s = x.x * x.x + x.y * x.y + x.z * x.z + x.w * x.w;
#pragma unroll
  for (int off = 32; off > 0; off >>= 1) s += __shfl_down(s, off);
  int lane = t & 63, wv = t >> 6;
  if (lane == 0) red[wv] = s;
  __syncthreads();
  if (t == 0) {
    float tot = red[0] + red[1] + red[2] + red[3];
    float norm = sqrtf(tot);
    float r = (norm > 1e-7f) ? (sinhf(norm) / fmaxf(norm, 1e-7f)) : 1.0f;
    r_sh = r;
    wtime[v] = coshf(norm);
  }
  __syncthreads();
  float r = r_sh;
  ushort4 pack;
  pack.x = f2bf(r * x.x);
  pack.y = f2bf(r * x.y);
  pack.z = f2bf(r * x.z);
  pack.w = f2bf(r * x.w);
  *(ushort4*)(wbf + (long)v * K_TOT + t * 4) = pack;
}

__global__ __launch_bounds__(256) void gemm_geo(
    const unsigned short* __restrict__ hbf, const unsigned short* __restrict__ wbf,
    const float* __restrict__ h0, const float* __restrict__ wtime,
    const float* __restrict__ ls, float* __restrict__ out) {
  __shared__ __align__(16) short lds[2][2][BM * BK];  // [buf][A=0,B=1][row*32+k]

  int bid = blockIdx.x;
  // XCD swizzle (8000 blocks % 8 == 0): contiguous 1000-block chunk per XCD;
  // within a chunk, 32 consecutive blocks share one B-panel (v-tile) -> L2 reuse.
  int s = (bid & 7) * 1000 + (bid >> 3);
  int tile_v = s / 32;  // [0,250)
  int tile_m = s % 32;  // [0,32)
  int row0 = tile_m * BM;
  int col0 = tile_v * BN;

  int t = threadIdx.x;
  int wave = t >> 6, lane = t & 63;

  auto stage = [&](int buf, int kt) {
#pragma unroll
    for (int i = 0; i < 2; ++i) {
      int tt = i * 256 + t;
      int r = tt >> 2, c = (tt & 3) * 8;
      const unsigned short* gA = hbf + (long)(row0 + r) * K_TOT + kt * BK + c;
      const unsigned short* gB = wbf + (long)(col0 + r) * K_TOT + kt * BK + c;
      int ldsoff = (i * 256 + wave * 64) * 8;  // shorts; HW adds lane*16B
      gload_lds16(gA, (void*)&lds[buf][0][ldsoff]);
      gload_lds16(gB, (void*)&lds[buf][1][ldsoff]);
    }
  };

  f32x4 acc[4][4];
#pragma unroll
  for (int i = 0; i < 4; ++i)
#pragma unroll
    for (int j = 0; j < 4; ++j) acc[i][j] = (f32x4)(0.0f);

  int wm = wave >> 1, wn = wave & 1;  // 2x2 wave grid, 64x64 per wave
  int fr = lane & 15, fq = lane >> 4;

  stage(0, 0);
  int cur = 0;
  for (int kt = 0; kt < NT; ++kt) {
    __syncthreads();  // staging of buf[cur] complete (compiler drains vmcnt)
    if (kt + 1 < NT) stage(cur ^ 1, kt + 1);
    short8 a[4], b[4];
#pragma unroll
    for (int mi = 0; mi < 4; ++mi) {
      int row = wm * 64 + mi * 16 + fr;
      a[mi] = *(const short8*)&lds[cur][0][row * BK + fq * 8];
    }
#pragma unroll
    for (int ni = 0; ni < 4; ++ni) {
      int row = wn * 64 + ni * 16 + fr;
      b[ni] = *(const short8*)&lds[cur][1][row * BK + fq * 8];
    }
#pragma unroll
    for (int mi = 0; mi < 4; ++mi)
#pragma unroll
      for (int ni = 0; ni < 4; ++ni)
        acc[mi][ni] = __builtin_amdgcn_mfma_f32_16x16x32_bf16(a[mi], b[ni], acc[mi][ni], 0, 0, 0);
    cur ^= 1;
  }

  // fused epilogue: x = h0*w_time - dot ; d2 = safe_acosh(x)^2 ; out = -tau*d2
  // Fast-math forms: v_sqrt_f32 raw, v_log_f32 (log2) * ln2. Taylor branch
  // computed in d^2 form (sqrt cancels); branchless select.
  float ntau = -fminf(fmaxf(ls[0], 0.01f), 2.5f);
  const float LN2 = 0.69314718055994531f;
  float wt[4];
#pragma unroll
  for (int ni = 0; ni < 4; ++ni) wt[ni] = wtime[col0 + wn * 64 + ni * 16 + fr];
#pragma unroll
  for (int mi = 0; mi < 4; ++mi) {
#pragma unroll
    for (int j = 0; j < 4; ++j) {
      int m = row0 + wm * 64 + mi * 16 + fq * 4 + j;
      float h0v = h0[m];
      float* orow = out + (long)m * V_TOT + col0 + wn * 64 + fr;
#pragma unroll
      for (int ni = 0; ni < 4; ++ni) {
        float dot = acc[mi][ni][j];
        float x = fmaf(h0v, wt[ni], -dot);
        float xm1 = fmaxf(x - 1.0f, 0.0f);
        // exact path: d = ln2 * log2(x + sqrt(x^2-1))
        float arg = fmaxf(fmaf(x, x, -1.0f), 0.0f);
        float lg2 = __builtin_amdgcn_logf(x + __builtin_amdgcn_sqrtf(arg));
        float dex = LN2 * lg2;
        float d2_exact = dex * dex;
        // taylor path in d^2 form: 2*xm1*(1 - xm1/12)^2
        float ts = fmaf(xm1, -1.0f / 12.0f, 1.0f);
        float d2_tay = 2.0f * xm1 * ts * ts;
        float d2 = (xm1 < 1e-3f) ? d2_tay : d2_exact;
        orow[ni * 16] = ntau * d2;
      }
    }
  }
}

extern "C" void kernel_launch(void* const* d_in, const int* in_sizes, int n_in,
                              void* d_out, int out_size, void* d_ws, size_t ws_size,
                              hipStream_t stream) {
  const float* h = (const float*)d_in[0];   // [2,2048,1025]
  const float* w = (const float*)d_in[1];   // [32000,1024]
  const float* ls = (const float*)d_in[2];  // scalar
  float* out = (float*)d_out;               // [2,2048,32000] fp32

  char* ws = (char*)d_ws;
  unsigned short* wbf = (unsigned short*)ws;                              // 65,536,000 B
  unsigned short* hbf = (unsigned short*)(ws + 65536000);                 // 8,388,608 B
  float* wtime = (float*)(ws + 65536000 + 8388608);                       // 128,000 B
  float* h0 = (float*)(ws + 65536000 + 8388608 + 128000);                 // 16,384 B

  prep_h<<<M_TOT, 256, 0, stream>>>(h, hbf, h0);
  prep_w<<<V_TOT, 256, 0, stream>>>(w, wbf, wtime);
  gemm_geo<<<8000, 256, 0, stream>>>(hbf, wbf, h0, wtime, ls, out);
}

// Round 3
// 391.822 us; speedup vs baseline: 1.4949x; 1.2824x over previous
//
#include <hip/hip_runtime.h>
#include <hip/hip_bf16.h>
#include <math.h>

#define M_TOT 4096
#define K_TOT 1024
#define V_TOT 32000

typedef short short8 __attribute__((ext_vector_type(8)));
typedef float f32x4 __attribute__((ext_vector_type(4)));

__device__ __forceinline__ void gload_lds16(const void* g, void* l) {
  __builtin_amdgcn_global_load_lds(
      (const __attribute__((address_space(1))) void*)g,
      (__attribute__((address_space(3))) void*)l, 16, 0, 0);
}

__device__ __forceinline__ unsigned short f2bf(float f) {
  unsigned int u = __builtin_bit_cast(unsigned int, f);
  unsigned int lsb = (u >> 16) & 1u;
  u += 0x7fffu + lsb;
  return (unsigned short)(u >> 16);
}

__device__ __forceinline__ float sani(float v) {
  return (v != v) ? 0.0f : fminf(fmaxf(v, -1e4f), 1e4f);
}

__global__ void prep_h(const float* __restrict__ h, unsigned short* __restrict__ hbf,
                       float* __restrict__ h0) {
  int m = blockIdx.x;
  int t = threadIdx.x;
  const float* row = h + (long)m * (K_TOT + 1);
  if (t == 0) h0[m] = sani(row[0]);
  unsigned short* dst = hbf + (long)m * K_TOT;
#pragma unroll
  for (int j = 0; j < 4; ++j) {
    int idx = t * 4 + j;
    dst[idx] = f2bf(sani(row[1 + idx]));
  }
}

__global__ void prep_w(const float* __restrict__ w, unsigned short* __restrict__ wbf,
                       float* __restrict__ wtime) {
  __shared__ float red[4];
  __shared__ float r_sh;
  int v = blockIdx.x;
  int t = threadIdx.x;
  const float* row = w + (long)v * K_TOT;
  float4 x = *(const float4*)(row + t * 4);
  float s = x.x * x.x + x.y * x.y + x.z * x.z + x.w * x.w;
#pragma unroll
  for (int off = 32; off > 0; off >>= 1) s += __shfl_down(s, off);
  int lane = t & 63, wv = t >> 6;
  if (lane == 0) red[wv] = s;
  __syncthreads();
  if (t == 0) {
    float tot = red[0] + red[1] + red[2] + red[3];
    float norm = sqrtf(tot);
    float r = (norm > 1e-7f) ? (sinhf(norm) / fmaxf(norm, 1e-7f)) : 1.0f;
    r_sh = r;
    wtime[v] = coshf(norm);
  }
  __syncthreads();
  float r = r_sh;
  ushort4 pack;
  pack.x = f2bf(r * x.x);
  pack.y = f2bf(r * x.y);
  pack.z = f2bf(r * x.z);
  pack.w = f2bf(r * x.w);
  *(ushort4*)(wbf + (long)v * K_TOT + t * 4) = pack;
}

// ---------------- 256x256 tile, BK=32, 8-wave phase-interleaved GEMM --------
// LDS layout (bytes): off = d*32768 + mat*16384 + row*64 + chunk*16
//   d = double-buffer (one 32-wide K-tile per buffer), mat: 0=A,1=B,
//   row 0..255 (tile-relative), chunk 0..3 (16B of 8 bf16).
// XOR swizzle: slot chunk c holds global k-chunk c ^ (row&3). gload_lds writes
// LINEARLY (thread t -> slot t*16, row=t/4, c=t%4), so the global SOURCE is
// pre-swizzled: thread t loads global chunk (t&3)^((t>>2)&3). ds_read applies
// the same XOR: chunk = fq ^ (fr&3). (rule #21: both-sides-or-neither)
#define BAR __builtin_amdgcn_s_barrier()
#define LGKM0 asm volatile("s_waitcnt lgkmcnt(0)" ::: "memory")
#define VM2 asm volatile("s_waitcnt vmcnt(2)" ::: "memory")
#define RD8(off) (*(const short8*)(smem + (off)))
#define DSA(d, mb)                                     \
  {                                                    \
    _Pragma("unroll") for (int i = 0; i < 4; ++i)      \
        af[i] = RD8(a_rd + (d)*32768 + ((mb) + i) * 1024); \
  }
#define DSB(d)                                         \
  {                                                    \
    _Pragma("unroll") for (int i = 0; i < 4; ++i)      \
        bf[i] = RD8(b_rd + (d)*32768 + i * 1024);      \
  }
#define MF16(mb)                                                              \
  {                                                                           \
    __builtin_amdgcn_s_setprio(1);                                            \
    _Pragma("unroll") for (int i = 0; i < 4; ++i)                             \
        _Pragma("unroll") for (int n = 0; n < 4; ++n) acc[(mb) + i][n] =      \
            __builtin_amdgcn_mfma_f32_16x16x32_bf16(af[i], bf[n],             \
                                                    acc[(mb) + i][n], 0, 0, 0); \
    __builtin_amdgcn_s_setprio(0);                                            \
  }

__global__ __launch_bounds__(512, 2) void gemm_geo(
    const unsigned short* __restrict__ hbf, const unsigned short* __restrict__ wbf,
    const float* __restrict__ h0, const float* __restrict__ wtime,
    const float* __restrict__ ls, float* __restrict__ out) {
  __shared__ __align__(16) char smem[65536];

  const int t = threadIdx.x;
  const int wave = t >> 6, lane = t & 63;
  const int fr = lane & 15, fq = lane >> 4;
  const int wm = wave >> 2, wn = wave & 3;  // 2 (M) x 4 (N) wave grid

  // XCD-bijective swizzle: 2000 blocks, 250/XCD; 16 consecutive blocks on an
  // XCD share one 512KB B-panel (L2-resident reuse window).
  int bid = blockIdx.x;
  int swz = (bid & 7) * 250 + (bid >> 3);
  int tile_v = swz >> 4;   // 0..124
  int tile_m = swz & 15;   // 0..15
  int row0 = tile_m * 256;
  int col0 = tile_v * 256;

  // ds_read lane bases (bytes)
  const int sw = (fq ^ (fr & 3)) * 16;
  const int a_rd = (wm * 128 + fr) * 64 + sw;           // + d*32768 + mi*1024
  const int b_rd = 16384 + (wn * 64 + fr) * 64 + sw;    // + d*32768 + ni*1024

  // stage: thread t covers (row=t>>2, chunk=t&3), global chunk pre-swizzled
  const int cc = (t & 3) ^ ((t >> 2) & 3);
  const unsigned short* pA = hbf + (long)(row0 + (t >> 2)) * K_TOT + cc * 8;
  const unsigned short* pB = wbf + (long)(col0 + (t >> 2)) * K_TOT + cc * 8;
  const int dst_w = wave * 1024;  // wave-uniform; HW adds lane*16

  auto STAGE_A = [&](int kt, int h, int d) {
    gload_lds16(pA + (long)h * 131072 + kt * 32,
                smem + d * 32768 + h * 8192 + dst_w);
  };
  auto STAGE_B = [&](int kt, int h, int d) {
    gload_lds16(pB + (long)h * 131072 + kt * 32,
                smem + d * 32768 + 16384 + h * 8192 + dst_w);
  };

  f32x4 acc[8][4];
#pragma unroll
  for (int i = 0; i < 8; ++i)
#pragma unroll
    for (int j = 0; j < 4; ++j) acc[i][j] = (f32x4)(0.0f);
  short8 af[4], bf[4];

  // prologue: K-tile0 (A,B) -> dbuf0; B of K-tile1 -> dbuf1 (steady-state
  // stagger). vmcnt(2): A0,B0 landed, B1 may fly.
  STAGE_A(0, 0, 0); STAGE_A(0, 1, 0);
  STAGE_B(0, 0, 0); STAGE_B(0, 1, 0);
  STAGE_B(1, 0, 1); STAGE_B(1, 1, 1);
  VM2;
  BAR;

#pragma unroll 1
  for (int I = 0; I < 16; ++I) {
    int sA1 = 2 * I + 1;                          // always valid (<=31)
    int s2 = (2 * I + 2 < 32) ? 2 * I + 2 : 31;   // clamped redundant stage
    int sB3 = (2 * I + 3 < 32) ? 2 * I + 3 : 31;
    // P1: compute kt=2I (dbuf0) m0-3; stage A(2I+1)->dbuf1
    DSA(0, 0); DSB(0);
    STAGE_A(sA1, 0, 1); STAGE_A(sA1, 1, 1);
    BAR; LGKM0;
    MF16(0);
    BAR;
    // P2: m4-7; stage B(2I+2)->dbuf0; vmcnt(2) => A(2I+1) landed
    DSA(0, 4);
    STAGE_B(s2, 0, 0); STAGE_B(s2, 1, 0);
    VM2;
    BAR; LGKM0;
    MF16(4);
    BAR;
    // P3: compute kt=2I+1 (dbuf1) m0-3; stage A(2I+2)->dbuf0
    DSA(1, 0); DSB(1);
    STAGE_A(s2, 0, 0); STAGE_A(s2, 1, 0);
    BAR; LGKM0;
    MF16(0);
    BAR;
    // P4: m4-7; stage B(2I+3)->dbuf1; vmcnt(2) => A(2I+2),B(2I+2) landed
    DSA(1, 4);
    STAGE_B(sB3, 0, 1); STAGE_B(sB3, 1, 1);
    VM2;
    BAR; LGKM0;
    MF16(4);
    BAR;
  }

  // fused epilogue: x = h0*w_time - dot; d2 = safe_acosh(x)^2; out = -tau*d2
  float ntau = -fminf(fmaxf(ls[0], 0.01f), 2.5f);
  const float LN2 = 0.69314718055994531f;
  float wt[4];
#pragma unroll
  for (int ni = 0; ni < 4; ++ni) wt[ni] = wtime[col0 + wn * 64 + ni * 16 + fr];
#pragma unroll
  for (int mi = 0; mi < 8; ++mi) {
#pragma unroll
    for (int j = 0; j < 4; ++j) {
      int m = row0 + wm * 128 + mi * 16 + fq * 4 + j;
      float h0v = h0[m];
      float* orow = out + (long)m * V_TOT + col0 + wn * 64 + fr;
#pragma unroll
      for (int ni = 0; ni < 4; ++ni) {
        float dot = acc[mi][ni][j];
        float x = fmaf(h0v, wt[ni], -dot);
        float xm1 = fmaxf(x - 1.0f, 0.0f);
        float arg = fmaxf(fmaf(x, x, -1.0f), 0.0f);
        float lg2 = __builtin_amdgcn_logf(x + __builtin_amdgcn_sqrtf(arg));
        float dex = LN2 * lg2;
        float d2_exact = dex * dex;
        float ts = fmaf(xm1, -1.0f / 12.0f, 1.0f);
        float d2_tay = 2.0f * xm1 * ts * ts;
        float d2 = (xm1 < 1e-3f) ? d2_tay : d2_exact;
        __builtin_nontemporal_store(ntau * d2, &orow[ni * 16]);
      }
    }
  }
}

extern "C" void kernel_launch(void* const* d_in, const int* in_sizes, int n_in,
                              void* d_out, int out_size, void* d_ws, size_t ws_size,
                              hipStream_t stream) {
  const float* h = (const float*)d_in[0];   // [2,2048,1025]
  const float* w = (const float*)d_in[1];   // [32000,1024]
  const float* ls = (const float*)d_in[2];  // scalar
  float* out = (float*)d_out;               // [2,2048,32000] fp32

  char* ws = (char*)d_ws;
  unsigned short* wbf = (unsigned short*)ws;                  // 65,536,000 B
  unsigned short* hbf = (unsigned short*)(ws + 65536000);     // 8,388,608 B
  float* wtime = (float*)(ws + 65536000 + 8388608);           // 128,000 B
  float* h0 = (float*)(ws + 65536000 + 8388608 + 128000);     // 16,384 B

  prep_h<<<M_TOT, 256, 0, stream>>>(h, hbf, h0);
  prep_w<<<V_TOT, 256, 0, stream>>>(w, wbf, wtime);
  gemm_geo<<<2000, 512, 0, stream>>>(hbf, wbf, h0, wtime, ls, out);
}